// Round 1
// baseline (710.230 us; speedup 1.0000x reference)
//
#include <hip/hip_runtime.h>
#include <hip/hip_bf16.h>
#include <math.h>

// Problem constants (fixed by setup_inputs)
#define B_    16
#define C_    256
#define P_    16384          // 128*128
#define K_    101            // num_class + 1
#define S_    17             // B + 1 slots per class
#define V_    1717           // K_ * S_
#define GN_   1792           // V_ padded to 14*128
#define KPAD_ 102            // class stride in LDS (dummy slot for OOB labels)
#define TEMP_ 0.07f
#define INV_SQRT_T 3.7796447300922720f   // 1/sqrt(0.07)

__device__ __forceinline__ void atomAddLds(float* p, float v) {
  __hip_atomic_fetch_add(p, v, __ATOMIC_RELAXED, __HIP_MEMORY_SCOPE_WORKGROUP);
}
__device__ __forceinline__ void atomAddGlb(float* p, float v) {
  __hip_atomic_fetch_add(p, v, __ATOMIC_RELAXED, __HIP_MEMORY_SCOPE_AGENT);
}

// ---------------------------------------------------------------------------
// K1: per-(batch,class) masked sums + counts.
// grid (16 tiles, 16 batch, 2 ch-halves), block 1024.
// LDS: s_acc[128ch][102cls] class-major so concurrent lane adds spread banks.
// ---------------------------------------------------------------------------
__global__ __launch_bounds__(1024) void k_segsum(
    const int* __restrict__ labels, const float* __restrict__ feats,
    float* __restrict__ sums, unsigned* __restrict__ counts) {
  __shared__ float s_acc[128 * KPAD_];
  __shared__ int s_lab[1024];
  __shared__ unsigned s_cnt[KPAD_];
  const int tile = blockIdx.x, b = blockIdx.y, zh = blockIdx.z;
  const int tid = threadIdx.x;
  for (int i = tid; i < 128 * KPAD_; i += 1024) s_acc[i] = 0.f;
  if (zh == 0 && tid < KPAD_) s_cnt[tid] = 0u;
  const int p0 = tile * 1024;
  int lab = labels[b * P_ + p0 + tid];
  if ((unsigned)lab > 100u) lab = 101;   // route OOB labels to dummy slot
  s_lab[tid] = lab;
  __syncthreads();
  if (zh == 0) atomicAdd(&s_cnt[lab], 1u);
  const int wv = tid >> 6, ln = tid & 63;
  const float* fb = feats + ((size_t)b * C_ + (size_t)zh * 128) * P_ + p0;
  for (int g = 0; g < 4; ++g) {
    const int pb = g * 256 + ln * 4;
    const int4 lv = *(const int4*)&s_lab[pb];
#pragma unroll
    for (int j = 0; j < 8; ++j) {
      const int cl = wv * 8 + j;
      const float4 f = *(const float4*)&fb[(size_t)cl * P_ + pb];
      float* base = s_acc + cl * KPAD_;
      atomAddLds(base + lv.x, f.x);
      atomAddLds(base + lv.y, f.y);
      atomAddLds(base + lv.z, f.z);
      atomAddLds(base + lv.w, f.w);
    }
  }
  __syncthreads();
  for (int i = tid; i < 128 * KPAD_; i += 1024) {
    const int cl = i / KPAD_, kk = i - cl * KPAD_;
    const float v = s_acc[i];
    if (kk < K_ && v != 0.f)
      atomAddGlb(&sums[((size_t)b * K_ + kk) * C_ + zh * 128 + cl], v);
  }
  if (zh == 0) {
    for (int i = tid; i < K_; i += 1024) {
      const unsigned cv = s_cnt[i];
      if (cv) atomicAdd(&counts[b * K_ + i], cv);
    }
  }
}

// ---------------------------------------------------------------------------
// K2: build normalized prototype slots (pre-scaled by 1/sqrt(T)), valid mask,
// per-class cnt, per-column weight, cnt_exist. grid K_ blocks, 256 threads.
// ---------------------------------------------------------------------------
__global__ __launch_bounds__(256) void k_protos(
    const float* __restrict__ sums, const unsigned* __restrict__ counts,
    const float* __restrict__ prototypes, float* __restrict__ Pm,
    int* __restrict__ valid, float* __restrict__ wcol,
    float* __restrict__ cntk, float* __restrict__ scal) {
  const int k = blockIdx.x;
  const int c = threadIdx.x;  // 0..255 = channel
  __shared__ float red[4];
  __shared__ int s_valid[S_];
  for (int s = 0; s < S_; ++s) {
    float val;
    int pres;
    if (s < B_) {
      const unsigned cb = counts[s * K_ + k];
      val = sums[((size_t)s * K_ + k) * C_ + c] / fmaxf((float)cb, 1.f);
      pres = (cb > 0u) && (k >= 1);
    } else {
      val = prototypes[k * C_ + c];
      pres = (k >= 1);
    }
    float ss = val * val;
#pragma unroll
    for (int o = 32; o > 0; o >>= 1) ss += __shfl_down(ss, o);
    if ((c & 63) == 0) red[c >> 6] = ss;
    __syncthreads();
    const float tot = red[0] + red[1] + red[2] + red[3];
    const float nrm = fmaxf(sqrtf(tot), 1e-12f);
    Pm[((size_t)k * S_ + s) * C_ + c] = pres ? (val / nrm) * INV_SQRT_T : 0.f;
    if (c == 0) s_valid[s] = pres;
    __syncthreads();
  }
  if (c == 0) {
    int cnt = 0;
    for (int s = 0; s < S_; ++s) cnt += s_valid[s];
    const float cf = (float)cnt;
    cntk[k] = cf;
    const float wv = 1.f / fmaxf(cf, 1.f);
    for (int s = 0; s < S_; ++s) {
      valid[k * S_ + s] = s_valid[s];
      wcol[k * S_ + s] = s_valid[s] ? wv : 0.f;
    }
    if (cnt > 1 && k >= 1) atomAddGlb(&scal[1], 1.f);
  }
}

// ---------------------------------------------------------------------------
// K3: Gram matrix G = Pm * Pm^T  (already includes 1/T since Pm scaled).
// 128x128 tiles, 8x8 per thread, fp32 VALU. grid (14,14), block 256.
// ---------------------------------------------------------------------------
__global__ __launch_bounds__(256) void k_gram(const float* __restrict__ Pm,
                                              float* __restrict__ G) {
  __shared__ float As[32][132];
  __shared__ float Bs[32][132];
  const int j0 = blockIdx.x * 128, i0 = blockIdx.y * 128;
  const int tid = threadIdx.x;
  const int tx = tid & 15, ty = tid >> 4;
  float acc[8][8];
#pragma unroll
  for (int q = 0; q < 8; ++q)
#pragma unroll
    for (int r = 0; r < 8; ++r) acc[q][r] = 0.f;
  for (int kc = 0; kc < C_; kc += 32) {
#pragma unroll
    for (int q = 0; q < 4; ++q) {
      const int lin = tid + q * 256;
      const int r = lin >> 3, kk = (lin & 7) << 2;
      const float4 va = *(const float4*)&Pm[(size_t)(i0 + r) * C_ + kc + kk];
      As[kk + 0][r] = va.x; As[kk + 1][r] = va.y;
      As[kk + 2][r] = va.z; As[kk + 3][r] = va.w;
      const float4 vb = *(const float4*)&Pm[(size_t)(j0 + r) * C_ + kc + kk];
      Bs[kk + 0][r] = vb.x; Bs[kk + 1][r] = vb.y;
      Bs[kk + 2][r] = vb.z; Bs[kk + 3][r] = vb.w;
    }
    __syncthreads();
#pragma unroll
    for (int kk = 0; kk < 32; ++kk) {
      const float4 a0 = *(const float4*)&As[kk][ty * 8];
      const float4 a1 = *(const float4*)&As[kk][ty * 8 + 4];
      const float4 b0 = *(const float4*)&Bs[kk][tx * 8];
      const float4 b1 = *(const float4*)&Bs[kk][tx * 8 + 4];
      const float av[8] = {a0.x, a0.y, a0.z, a0.w, a1.x, a1.y, a1.z, a1.w};
      const float bv[8] = {b0.x, b0.y, b0.z, b0.w, b1.x, b1.y, b1.z, b1.w};
#pragma unroll
      for (int q = 0; q < 8; ++q)
#pragma unroll
        for (int r = 0; r < 8; ++r) acc[q][r] = fmaf(av[q], bv[r], acc[q][r]);
    }
    __syncthreads();
  }
#pragma unroll
  for (int q = 0; q < 8; ++q) {
    float4 o0 = {acc[q][0], acc[q][1], acc[q][2], acc[q][3]};
    float4 o1 = {acc[q][4], acc[q][5], acc[q][6], acc[q][7]};
    float* gr = &G[(size_t)(i0 + ty * 8 + q) * GN_ + j0 + tx * 8];
    *(float4*)gr = o0;
    *(float4*)(gr + 4) = o1;
  }
}

// ---------------------------------------------------------------------------
// K4: per-anchor loss. grid (16 slots, 101 classes), block 256.
// ---------------------------------------------------------------------------
__global__ __launch_bounds__(256) void k_loss(
    const float* __restrict__ G, const int* __restrict__ valid,
    const float* __restrict__ wcol, const float* __restrict__ cntk,
    float* __restrict__ scal) {
  const int s = blockIdx.x;  // 0..15 (batch slots only = anchors)
  const int k = blockIdx.y;  // 0..100
  const int a = k * S_ + s;
  if (!valid[a]) return;  // uniform over block
  const int tid = threadIdx.x;
  const float* row = G + (size_t)a * GN_;
  float dpart = 0.f;
  for (int j = tid; j < GN_; j += 256) dpart += wcol[j] * __expf(row[j]);
  __shared__ float red[4];
#pragma unroll
  for (int o = 32; o > 0; o >>= 1) dpart += __shfl_down(dpart, o);
  if ((tid & 63) == 0) red[tid >> 6] = dpart;
  __syncthreads();
  if (tid == 0) {
    const float den = red[0] + red[1] + red[2] + red[3];
    float pos = 0.f;
    for (int n = 0; n < S_; ++n)
      if (valid[k * S_ + n]) pos += row[k * S_ + n];
    pos -= row[a];  // remove self term (diag)
    const float np = cntk[k] - 1.f;
    const float npc = fmaxf(np, 1.f);
    const float pa = -(pos - np * logf(den)) / (npc * npc);
    atomAddGlb(&scal[0], pa);
  }
}

__global__ void k_final(const float* __restrict__ scal, float* __restrict__ out) {
  out[0] = 0.1f * scal[0] / scal[1];
}

// ---------------------------------------------------------------------------
extern "C" void kernel_launch(void* const* d_in, const int* in_sizes, int n_in,
                              void* d_out, int out_size, void* d_ws, size_t ws_size,
                              hipStream_t stream) {
  const int* labels = (const int*)d_in[0];
  const float* feats = (const float*)d_in[1];
  const float* protos = (const float*)d_in[2];
  float* out = (float*)d_out;

  char* wsb = (char*)d_ws;
  size_t o = 0;
  auto nxt = [&](size_t bytes) {
    size_t r = o;
    o = (o + bytes + 255) & ~(size_t)255;
    return r;
  };
  const size_t off_sums = nxt((size_t)B_ * K_ * C_ * 4);
  const size_t off_cnts = nxt((size_t)B_ * K_ * 4);
  const size_t off_P    = nxt((size_t)GN_ * C_ * 4);
  const size_t off_val  = nxt((size_t)GN_ * 4);
  const size_t off_w    = nxt((size_t)GN_ * 4);
  const size_t off_cntk = nxt((size_t)K_ * 4);
  const size_t off_scal = nxt(8);
  const size_t off_G    = nxt((size_t)GN_ * GN_ * 4);
  (void)off_G;

  float* w_sums    = (float*)(wsb + off_sums);
  unsigned* w_cnts = (unsigned*)(wsb + off_cnts);
  float* w_P       = (float*)(wsb + off_P);
  int* w_valid     = (int*)(wsb + off_val);
  float* w_w       = (float*)(wsb + off_w);
  float* w_cntk    = (float*)(wsb + off_cntk);
  float* w_scal    = (float*)(wsb + off_scal);
  float* w_G       = (float*)(wsb + off_G);

  // Zero everything before G (sums/counts/P-pad/valid/w/cntk/scalars).
  hipMemsetAsync(d_ws, 0, off_G, stream);

  k_segsum<<<dim3(16, 16, 2), 1024, 0, stream>>>(labels, feats, w_sums, w_cnts);
  k_protos<<<K_, 256, 0, stream>>>(w_sums, w_cnts, protos, w_P, w_valid, w_w,
                                   w_cntk, w_scal);
  k_gram<<<dim3(GN_ / 128, GN_ / 128), 256, 0, stream>>>(w_P, w_G);
  k_loss<<<dim3(B_, K_), 256, 0, stream>>>(w_G, w_valid, w_w, w_cntk, w_scal);
  k_final<<<1, 1, 0, stream>>>(w_scal, out);
}